// Round 6
// baseline (255.264 us; speedup 1.0000x reference)
//
#include <hip/hip_runtime.h>
#include <stdint.h>

constexpr int SEQ  = 2048;
constexpr int DIM  = 1024;
constexpr int NH   = 16;
constexpr int HDIM = 64;
constexpr int TOPK = 16;
constexpr int CAP  = 96;   // candidate buffer per row (expected fill ~20-40)
constexpr int CST  = 97;   // padded stride
constexpr int QR   = 32;   // q-rows per attn block

typedef unsigned short bf16_t;
typedef __attribute__((ext_vector_type(8))) short bf16x8;
typedef __attribute__((ext_vector_type(4))) float f32x4;
typedef unsigned long long u64;

// T2 XOR swizzle (round-2: GEMM LDS conflicts 1.28e7 -> 1.9e5)
__device__ __forceinline__ int swzc(int col, int row) { return col ^ ((row & 7) << 3); }

__device__ __forceinline__ float bf2f(bf16_t b) {
  return __uint_as_float(((unsigned)b) << 16);
}
__device__ __forceinline__ bf16_t f2bf(float f) {
  unsigned u = __float_as_uint(f);
  unsigned r = u + 0x7fffu + ((u >> 16) & 1u);
  return (bf16_t)(r >> 16);
}
__device__ __forceinline__ f32x4 zero4() {
  f32x4 z; z[0] = 0.f; z[1] = 0.f; z[2] = 0.f; z[3] = 0.f; return z;
}
__device__ __forceinline__ void gload_lds16(const bf16_t* g, bf16_t* l) {
  __builtin_amdgcn_global_load_lds(
      (const __attribute__((address_space(1))) void*)g,
      (__attribute__((address_space(3))) void*)l, 16, 0, 0);
}
// monotone float->uint order transform
__device__ __forceinline__ unsigned ordf(float f) {
  unsigned b = __float_as_uint(f);
  return (b & 0x80000000u) ? ~b : (b | 0x80000000u);
}
__device__ __forceinline__ float iordf(unsigned u) {
  unsigned b = (u & 0x80000000u) ? (u ^ 0x80000000u) : ~u;
  return __uint_as_float(b);
}

// ---------------- prep: weight transpose+cast (z<4) and x cast (z==4) ----------------
__global__ void prep_kernel(const float* __restrict__ x, bf16_t* __restrict__ xb,
                            const float* __restrict__ W0, const float* __restrict__ W1,
                            const float* __restrict__ W2, const float* __restrict__ W3,
                            bf16_t* __restrict__ T0, bf16_t* __restrict__ T1,
                            bf16_t* __restrict__ T2, bf16_t* __restrict__ T3) {
  const int z = blockIdx.z;
  if (z == 4) {
    int bl = blockIdx.y * 32 + blockIdx.x;
    int tt = threadIdx.y * 32 + threadIdx.x;
    int i = (bl * 256 + tt) * 8;
    float4 v0 = *reinterpret_cast<const float4*>(x + i);
    float4 v1 = *reinterpret_cast<const float4*>(x + i + 4);
    bf16x8 o;
    o[0] = (short)f2bf(v0.x); o[1] = (short)f2bf(v0.y);
    o[2] = (short)f2bf(v0.z); o[3] = (short)f2bf(v0.w);
    o[4] = (short)f2bf(v1.x); o[5] = (short)f2bf(v1.y);
    o[6] = (short)f2bf(v1.z); o[7] = (short)f2bf(v1.w);
    *reinterpret_cast<bf16x8*>(xb + i) = o;
    return;
  }
  const float* W = (z == 0) ? W0 : (z == 1) ? W1 : (z == 2) ? W2 : W3;
  bf16_t* WT = (z == 0) ? T0 : (z == 1) ? T1 : (z == 2) ? T2 : T3;
  __shared__ float tile[32][33];
  int tx = threadIdx.x, ty = threadIdx.y;
  int bx = blockIdx.x * 32, by = blockIdx.y * 32;
#pragma unroll
  for (int i = 0; i < 4; ++i)
    tile[ty + i * 8][tx] = W[(by + ty + i * 8) * DIM + bx + tx];
  __syncthreads();
#pragma unroll
  for (int i = 0; i < 4; ++i)
    WT[(bx + ty + i * 8) * DIM + by + tx] = f2bf(tile[tx][ty + i * 8]);
}

// ---------------- GEMM 128x128 tile (m97 structure), BK=64, dbuf, swizzled LDS -------
// MODE 0: QKV fused (bf16 out + V col-sums), grid (24,16): which = x>>3, bn0=(x&7)*128
// MODE 1: Wo split-K x2 (f32 atomicAdd out, bias on kz==0), grid (8,16,2)
template <int MODE>
__global__ __launch_bounds__(256) void gemm_t(const bf16_t* __restrict__ A,
                                              const bf16_t* __restrict__ B0,
                                              const bf16_t* __restrict__ B1,
                                              const bf16_t* __restrict__ B2,
                                              const float* __restrict__ c0,
                                              const float* __restrict__ c1,
                                              const float* __restrict__ c2,
                                              void* __restrict__ o0,
                                              void* __restrict__ o1,
                                              void* __restrict__ o2,
                                              float* __restrict__ sumv) {
  __shared__ __align__(16) bf16_t As[2][128 * 64];
  __shared__ __align__(16) bf16_t Bs[2][128 * 64];
  const int t = threadIdx.x;
  int which, bn0, ks0, nst;
  if (MODE == 0) {
    which = blockIdx.x >> 3; bn0 = (blockIdx.x & 7) * 128; ks0 = 0; nst = 16;
  } else {
    which = 0; bn0 = blockIdx.x * 128; ks0 = blockIdx.z * 8; nst = 8;
  }
  const bf16_t* Bt = (which == 0) ? B0 : (which == 1) ? B1 : B2;
  const float* bias = (which == 0) ? c0 : (which == 1) ? c1 : c2;
  void* out = (which == 0) ? o0 : (which == 1) ? o1 : o2;
  const int bm0 = blockIdx.y * 128;
  const int w = t >> 6, lane = t & 63, lr = lane & 15, lg = lane >> 4;
  const int wm = w >> 1, wn = w & 1;
  const int srow = t >> 3;
  const int scol = swzc((t & 7) * 8, srow);
  const int ldst = srow * 64 + (t & 7) * 8;
  const int rsw = (lr & 7) << 3;

  f32x4 acc[4][4];
#pragma unroll
  for (int m = 0; m < 4; ++m)
#pragma unroll
    for (int n = 0; n < 4; ++n) acc[m][n] = zero4();

#define STAGE_G(buf, kt)                                                             \
  do {                                                                               \
    _Pragma("unroll") for (int i_ = 0; i_ < 4; ++i_) {                               \
      gload_lds16(A + (size_t)(bm0 + i_ * 32 + srow) * DIM + (kt) * 64 + scol,       \
                  &As[buf][i_ * 32 * 64 + ldst]);                                    \
      gload_lds16(Bt + (size_t)(bn0 + i_ * 32 + srow) * DIM + (kt) * 64 + scol,      \
                  &Bs[buf][i_ * 32 * 64 + ldst]);                                    \
    }                                                                                \
  } while (0)

  STAGE_G(0, ks0);
  __syncthreads();

  for (int s = 0; s < nst; ++s) {
    const int cur = s & 1;
    if (s < nst - 1) STAGE_G(cur ^ 1, ks0 + s + 1);
    bf16x8 a[4][2], b[4][2];
#pragma unroll
    for (int m = 0; m < 4; ++m)
#pragma unroll
      for (int kk = 0; kk < 2; ++kk)
        a[m][kk] = *reinterpret_cast<const bf16x8*>(
            &As[cur][(wm * 64 + m * 16 + lr) * 64 + ((kk * 32 + lg * 8) ^ rsw)]);
#pragma unroll
    for (int n = 0; n < 4; ++n)
#pragma unroll
      for (int kk = 0; kk < 2; ++kk)
        b[n][kk] = *reinterpret_cast<const bf16x8*>(
            &Bs[cur][(wn * 64 + n * 16 + lr) * 64 + ((kk * 32 + lg * 8) ^ rsw)]);
#pragma unroll
    for (int m = 0; m < 4; ++m)
#pragma unroll
      for (int n = 0; n < 4; ++n)
#pragma unroll
        for (int kk = 0; kk < 2; ++kk)
          acc[m][n] = __builtin_amdgcn_mfma_f32_16x16x32_bf16(a[m][kk], b[n][kk],
                                                              acc[m][n], 0, 0, 0);
    __syncthreads();
  }
#undef STAGE_G

#pragma unroll
  for (int n = 0; n < 4; ++n) {
    int col = bn0 + wn * 64 + n * 16 + lr;
    float bv = bias[col];
    if (MODE == 0) {
      float colsum = 0.f;
#pragma unroll
      for (int m = 0; m < 4; ++m)
#pragma unroll
        for (int r = 0; r < 4; ++r) {
          int row = bm0 + wm * 64 + m * 16 + lg * 4 + r;
          bf16_t rb = f2bf(acc[m][n][r] + bv);
          reinterpret_cast<bf16_t*>(out)[(size_t)row * DIM + col] = rb;
          if (which == 2) colsum += bf2f(rb);
        }
      if (which == 2) atomicAdd(&sumv[col], colsum);
    } else {
      float badd = (ks0 == 0) ? bv : 0.f;
#pragma unroll
      for (int m = 0; m < 4; ++m)
#pragma unroll
        for (int r = 0; r < 4; ++r) {
          int row = bm0 + wm * 64 + m * 16 + lg * 4 + r;
          atomicAdd(reinterpret_cast<float*>(out) + (size_t)row * DIM + col,
                    acc[m][n][r] + badd);
        }
    }
  }
}

// ---------------- attn v5: swapped-operand MFMA, 32-row blocks, 4 blocks/CU ----------
// 256 threads = 4 waves; 32 q-rows x one head; wave w owns k-chunks [w*8, w*8+8).
// mfma(K,Q): lane holds q-row = m*16 + (lane&15), k = kc*64 + n*16 + (lane>>4)*4 + r.
#define LOADK(buf, kc)                                                              \
  do {                                                                              \
    _Pragma("unroll") for (int n_ = 0; n_ < 4; ++n_)                                \
      _Pragma("unroll") for (int k_ = 0; k_ < 2; ++k_)                              \
        kf[buf][n_][k_] = *reinterpret_cast<const bf16x8*>(                         \
            kp + (size_t)((kc) * 64 + n_ * 16 + lr) * DIM + k_ * 32 + lg * 8);      \
  } while (0)

__global__ __launch_bounds__(256, 4) void attn_kernel(const bf16_t* __restrict__ q,
                                                      const bf16_t* __restrict__ k,
                                                      const bf16_t* __restrict__ v,
                                                      const float* __restrict__ sumv,
                                                      bf16_t* __restrict__ op) {
  __shared__ float CM[QR * 33];
  __shared__ float Tsh[QR];
  __shared__ float zsh[QR];
  __shared__ int   cnt[QR];
  __shared__ float cval[QR * CST];
  __shared__ unsigned short cidx[QR * CST];

  const int t = threadIdx.x;
  // XCD-aware bijective remap (1024 blocks): 2 heads per XCD -> head slices L2-resident
  const int lin = blockIdx.x;
  const int xcd = lin & 7, ixd = lin >> 3;
  const int h = xcd * 2 + (ixd >> 6), qt = ixd & 63;
  const int w = t >> 6, lane = t & 63, lr = lane & 15, lg = lane >> 4;

  const bf16_t* qp = q + (size_t)(qt * QR) * DIM + h * HDIM;
  const bf16_t* kp = k + h * HDIM;

  bf16x8 aq[2][2];
#pragma unroll
  for (int m = 0; m < 2; ++m)
#pragma unroll
    for (int kk = 0; kk < 2; ++kk)
      aq[m][kk] = *reinterpret_cast<const bf16x8*>(
          qp + (size_t)(m * 16 + lr) * DIM + kk * 32 + lg * 8);

  bf16x8 kf[2][4][2];

  // ---- pass 1: per-(row,chunk) maxima (swapped mfma -> in-lane max + 2 shfl) ----
  LOADK(0, w * 8);
#pragma unroll
  for (int i = 0; i < 8; ++i) {
    if (i < 7) LOADK((i + 1) & 1, w * 8 + i + 1);
    const int cur = i & 1;
    f32x4 sacc[2][4];
#pragma unroll
    for (int m = 0; m < 2; ++m)
#pragma unroll
      for (int n = 0; n < 4; ++n) sacc[m][n] = zero4();
#pragma unroll
    for (int m = 0; m < 2; ++m)
#pragma unroll
      for (int n = 0; n < 4; ++n)
#pragma unroll
        for (int kk = 0; kk < 2; ++kk)
          sacc[m][n] = __builtin_amdgcn_mfma_f32_16x16x32_bf16(kf[cur][n][kk], aq[m][kk],
                                                               sacc[m][n], 0, 0, 0);
#pragma unroll
    for (int m = 0; m < 2; ++m) {
      float mx = sacc[m][0][0];
#pragma unroll
      for (int n = 0; n < 4; ++n)
#pragma unroll
        for (int r = 0; r < 4; ++r) mx = fmaxf(mx, sacc[m][n][r]);
      mx = fmaxf(mx, __shfl_xor(mx, 16));
      mx = fmaxf(mx, __shfl_xor(mx, 32));
      if (lane < 16) CM[(m * 16 + lane) * 33 + (w * 8 + i)] = mx * 0.125f;
    }
  }
  LOADK(0, w * 8);  // prefetch pass-2 first tile across the threshold phase
  __syncthreads();

  // ---- threshold: T = 16th-largest chunk-max, 8 lanes per row ----
  {
    const int trow = t >> 3, tsub = t & 7;
    float cmv[4];
#pragma unroll
    for (int c = 0; c < 4; ++c) cmv[c] = CM[trow * 33 + tsub * 4 + c];
    float Tval = -1e30f;
#pragma unroll
    for (int it = 0; it < TOPK; ++it) {
      float lm = fmaxf(fmaxf(cmv[0], cmv[1]), fmaxf(cmv[2], cmv[3]));
      float gm = fmaxf(lm, __shfl_xor(lm, 1));
      gm = fmaxf(gm, __shfl_xor(gm, 2));
      gm = fmaxf(gm, __shfl_xor(gm, 4));
      u64 b = __ballot(lm == gm);
      int base = lane & ~7;
      int ownsub = __ffsll((b >> base) & 0xFFull) - 1;
      if (tsub == ownsub) {
        bool d = false;
#pragma unroll
        for (int c = 0; c < 4; ++c)
          if (!d && cmv[c] == lm) { cmv[c] = -1e30f; d = true; }
      }
      Tval = gm;
    }
    if (tsub == 0) { Tsh[trow] = Tval; cnt[trow] = 0; }
  }
  __syncthreads();

  float Treg[2];
#pragma unroll
  for (int m = 0; m < 2; ++m) Treg[m] = Tsh[m * 16 + lr];

  // ---- pass 2: recompute scores, collect candidates >= T ----
#pragma unroll
  for (int i = 0; i < 8; ++i) {
    if (i < 7) LOADK((i + 1) & 1, w * 8 + i + 1);
    const int cur = i & 1;
    const int kc = w * 8 + i;
    f32x4 sacc[2][4];
#pragma unroll
    for (int m = 0; m < 2; ++m)
#pragma unroll
      for (int n = 0; n < 4; ++n) sacc[m][n] = zero4();
#pragma unroll
    for (int m = 0; m < 2; ++m)
#pragma unroll
      for (int n = 0; n < 4; ++n)
#pragma unroll
        for (int kk = 0; kk < 2; ++kk)
          sacc[m][n] = __builtin_amdgcn_mfma_f32_16x16x32_bf16(kf[cur][n][kk], aq[m][kk],
                                                               sacc[m][n], 0, 0, 0);
#pragma unroll
    for (int m = 0; m < 2; ++m)
#pragma unroll
      for (int n = 0; n < 4; ++n)
#pragma unroll
        for (int r = 0; r < 4; ++r) {
          float val = sacc[m][n][r] * 0.125f;
          if (val >= Treg[m]) {
            int row = m * 16 + lr;
            int p = atomicAdd(&cnt[row], 1);
            if (p < CAP) {
              cval[row * CST + p] = val;
              cidx[row * CST + p] = (unsigned short)(kc * 64 + n * 16 + lg * 4 + r);
            }
          }
        }
  }
  __syncthreads();

  // ---- pass 3: exact top-16 (value order, lower-index tie-break), 8 lanes/row ----
  {
    const int trow = t >> 3, tsub = t & 7;
    int nc = cnt[trow]; if (nc > CAP) nc = CAP;
    float Zexp = 0.f;
    for (int sel = 0; sel < TOPK; ++sel) {
      u64 lmax = 0ull; int lp = -1;
      for (int p = tsub; p < nc; p += 8) {
        float vv = cval[trow * CST + p];
        unsigned id = cidx[trow * CST + p];
        u64 key = ((u64)ordf(vv) << 32) | (u64)(unsigned)(~id);
        if (key > lmax) { lmax = key; lp = p; }
      }
      u64 g = lmax;
#pragma unroll
      for (int d = 1; d < 8; d <<= 1) {
        u64 o = __shfl_xor(g, d);
        g = (o > g) ? o : g;
      }
      if (lmax == g && lp >= 0) cval[trow * CST + lp] = -1e30f;
      float val = iordf((unsigned)(g >> 32));
      int idx = (int)(~(unsigned)(g & 0xffffffffull));
      float e = expf(val);
      Zexp += e;
      if (tsub == 0) {
        CM[trow * 33 + sel] = e - 1.f;
        CM[trow * 33 + 16 + sel] = __int_as_float(idx);
      }
    }
    if (tsub == 0) zsh[trow] = 2032.f + Zexp;  // (2048-16) zeros give exp(0)=1
  }
  __syncthreads();

  // ---- pass 4: out = (sumv + sum_j w_j * v[idx_j]) / Z ----
  {
    const int row = t >> 3;
    const int dbase = h * HDIM + (t & 7) * 8;
    float oacc[8];
    const float4* sp = reinterpret_cast<const float4*>(sumv + dbase);
    float4 s0 = sp[0], s1 = sp[1];
    oacc[0] = s0.x; oacc[1] = s0.y; oacc[2] = s0.z; oacc[3] = s0.w;
    oacc[4] = s1.x; oacc[5] = s1.y; oacc[6] = s1.z; oacc[7] = s1.w;
    float invZ = 1.f / zsh[row];
#pragma unroll
    for (int j = 0; j < TOPK; ++j) {
      float wj = CM[row * 33 + j];
      int kidx = __float_as_int(CM[row * 33 + 16 + j]);
      bf16x8 vv = *reinterpret_cast<const bf16x8*>(v + (size_t)kidx * DIM + dbase);
#pragma unroll
      for (int e = 0; e < 8; ++e) oacc[e] += wj * bf2f((bf16_t)vv[e]);
    }
    bf16x8 o0;
#pragma unroll
    for (int e = 0; e < 8; ++e) o0[e] = (short)f2bf(oacc[e] * invZ);
    *reinterpret_cast<bf16x8*>(op + (size_t)(qt * QR + row) * DIM + dbase) = o0;
  }
}

extern "C" void kernel_launch(void* const* d_in, const int* in_sizes, int n_in,
                              void* d_out, int out_size, void* d_ws, size_t ws_size,
                              hipStream_t stream) {
  const float* x  = (const float*)d_in[0];
  const float* Wq = (const float*)d_in[1];
  const float* bq = (const float*)d_in[2];
  const float* Wk = (const float*)d_in[3];
  const float* bk = (const float*)d_in[4];
  const float* Wv = (const float*)d_in[5];
  const float* bv = (const float*)d_in[6];
  const float* Wo = (const float*)d_in[7];
  const float* bo = (const float*)d_in[8];
  float* out = (float*)d_out;

  char* ws = (char*)d_ws;
  bf16_t* xb   = (bf16_t*)(ws + (size_t)(0)  * (1 << 20));
  bf16_t* WqT  = (bf16_t*)(ws + (size_t)(4)  * (1 << 20));
  bf16_t* WkT  = (bf16_t*)(ws + (size_t)(6)  * (1 << 20));
  bf16_t* WvT  = (bf16_t*)(ws + (size_t)(8)  * (1 << 20));
  bf16_t* WoT  = (bf16_t*)(ws + (size_t)(10) * (1 << 20));
  bf16_t* qb   = (bf16_t*)(ws + (size_t)(12) * (1 << 20));
  bf16_t* kb   = (bf16_t*)(ws + (size_t)(16) * (1 << 20));
  bf16_t* vb   = (bf16_t*)(ws + (size_t)(20) * (1 << 20));
  bf16_t* opb  = (bf16_t*)(ws + (size_t)(24) * (1 << 20));
  float*  sumv = (float*) (ws + (size_t)(28) * (1 << 20));

  prep_kernel<<<dim3(32, 32, 5), dim3(32, 8), 0, stream>>>(x, xb, Wq, Wk, Wv, Wo,
                                                           WqT, WkT, WvT, WoT);
  hipMemsetAsync(sumv, 0, DIM * sizeof(float), stream);
  hipMemsetAsync(out, 0, (size_t)SEQ * DIM * sizeof(float), stream);

  gemm_t<0><<<dim3(24, 16), 256, 0, stream>>>(xb, WqT, WkT, WvT, bq, bk, bv,
                                              (void*)qb, (void*)kb, (void*)vb, sumv);

  attn_kernel<<<1024, 256, 0, stream>>>(qb, kb, vb, sumv, opb);

  gemm_t<1><<<dim3(8, 16, 2), 256, 0, stream>>>(opb, WoT, WoT, WoT, bo, bo, bo,
                                                (void*)out, (void*)out, (void*)out, sumv);
}

// Round 7
// 232.347 us; speedup vs baseline: 1.0986x; 1.0986x over previous
//
#include <hip/hip_runtime.h>
#include <stdint.h>

constexpr int SEQ  = 2048;
constexpr int DIM  = 1024;
constexpr int NH   = 16;
constexpr int HDIM = 64;
constexpr int TOPK = 16;
constexpr int CAP  = 96;   // candidate buffer per row (expected fill ~20-40)
constexpr int CST  = 97;   // padded stride
constexpr int QR   = 32;   // q-rows per attn block

typedef unsigned short bf16_t;
typedef __attribute__((ext_vector_type(8))) short bf16x8;
typedef __attribute__((ext_vector_type(4))) float f32x4;
typedef unsigned long long u64;

// T2 XOR swizzle (round-2: GEMM LDS conflicts 1.28e7 -> 1.9e5)
__device__ __forceinline__ int swzc(int col, int row) { return col ^ ((row & 7) << 3); }

__device__ __forceinline__ float bf2f(bf16_t b) {
  return __uint_as_float(((unsigned)b) << 16);
}
__device__ __forceinline__ bf16_t f2bf(float f) {
  unsigned u = __float_as_uint(f);
  unsigned r = u + 0x7fffu + ((u >> 16) & 1u);
  return (bf16_t)(r >> 16);
}
__device__ __forceinline__ f32x4 zero4() {
  f32x4 z; z[0] = 0.f; z[1] = 0.f; z[2] = 0.f; z[3] = 0.f; return z;
}
__device__ __forceinline__ void gload_lds16(const bf16_t* g, bf16_t* l) {
  __builtin_amdgcn_global_load_lds(
      (const __attribute__((address_space(1))) void*)g,
      (__attribute__((address_space(3))) void*)l, 16, 0, 0);
}
// monotone float->uint order transform
__device__ __forceinline__ unsigned ordf(float f) {
  unsigned b = __float_as_uint(f);
  return (b & 0x80000000u) ? ~b : (b | 0x80000000u);
}
__device__ __forceinline__ float iordf(unsigned u) {
  unsigned b = (u & 0x80000000u) ? (u ^ 0x80000000u) : ~u;
  return __uint_as_float(b);
}

// ---------------- prep: weight transpose+cast (z<4) and x cast (z==4) ----------------
__global__ void prep_kernel(const float* __restrict__ x, bf16_t* __restrict__ xb,
                            const float* __restrict__ W0, const float* __restrict__ W1,
                            const float* __restrict__ W2, const float* __restrict__ W3,
                            bf16_t* __restrict__ T0, bf16_t* __restrict__ T1,
                            bf16_t* __restrict__ T2, bf16_t* __restrict__ T3) {
  const int z = blockIdx.z;
  if (z == 4) {
    int bl = blockIdx.y * 32 + blockIdx.x;
    int tt = threadIdx.y * 32 + threadIdx.x;
    int i = (bl * 256 + tt) * 8;
    float4 v0 = *reinterpret_cast<const float4*>(x + i);
    float4 v1 = *reinterpret_cast<const float4*>(x + i + 4);
    bf16x8 o;
    o[0] = (short)f2bf(v0.x); o[1] = (short)f2bf(v0.y);
    o[2] = (short)f2bf(v0.z); o[3] = (short)f2bf(v0.w);
    o[4] = (short)f2bf(v1.x); o[5] = (short)f2bf(v1.y);
    o[6] = (short)f2bf(v1.z); o[7] = (short)f2bf(v1.w);
    *reinterpret_cast<bf16x8*>(xb + i) = o;
    return;
  }
  const float* W = (z == 0) ? W0 : (z == 1) ? W1 : (z == 2) ? W2 : W3;
  bf16_t* WT = (z == 0) ? T0 : (z == 1) ? T1 : (z == 2) ? T2 : T3;
  __shared__ float tile[32][33];
  int tx = threadIdx.x, ty = threadIdx.y;
  int bx = blockIdx.x * 32, by = blockIdx.y * 32;
#pragma unroll
  for (int i = 0; i < 4; ++i)
    tile[ty + i * 8][tx] = W[(by + ty + i * 8) * DIM + bx + tx];
  __syncthreads();
#pragma unroll
  for (int i = 0; i < 4; ++i)
    WT[(bx + ty + i * 8) * DIM + by + tx] = f2bf(tile[tx][ty + i * 8]);
}

// ---------------- QKV GEMM: 128x128 tile, BK=64, dbuf, swizzled LDS ------------------
// grid (24,16): which = x>>3 selects {Wq,Wk,Wv}; V col-sums fused via atomics.
__global__ __launch_bounds__(256) void gemm_qkv(const bf16_t* __restrict__ A,
                                                const bf16_t* __restrict__ B0,
                                                const bf16_t* __restrict__ B1,
                                                const bf16_t* __restrict__ B2,
                                                const float* __restrict__ c0,
                                                const float* __restrict__ c1,
                                                const float* __restrict__ c2,
                                                bf16_t* __restrict__ o0,
                                                bf16_t* __restrict__ o1,
                                                bf16_t* __restrict__ o2,
                                                float* __restrict__ sumv) {
  __shared__ __align__(16) bf16_t As[2][128 * 64];
  __shared__ __align__(16) bf16_t Bs[2][128 * 64];
  const int t = threadIdx.x;
  const int which = blockIdx.x >> 3;
  const bf16_t* Bt = (which == 0) ? B0 : (which == 1) ? B1 : B2;
  const float* bias = (which == 0) ? c0 : (which == 1) ? c1 : c2;
  bf16_t* out = (which == 0) ? o0 : (which == 1) ? o1 : o2;
  const int bm0 = blockIdx.y * 128, bn0 = (blockIdx.x & 7) * 128;
  const int w = t >> 6, lane = t & 63, lr = lane & 15, lg = lane >> 4;
  const int wm = w >> 1, wn = w & 1;
  const int srow = t >> 3;
  const int scol = swzc((t & 7) * 8, srow);
  const int ldst = srow * 64 + (t & 7) * 8;
  const int rsw = (lr & 7) << 3;

  f32x4 acc[4][4];
#pragma unroll
  for (int m = 0; m < 4; ++m)
#pragma unroll
    for (int n = 0; n < 4; ++n) acc[m][n] = zero4();

#define STAGE_G(buf, kt)                                                             \
  do {                                                                               \
    _Pragma("unroll") for (int i_ = 0; i_ < 4; ++i_) {                               \
      gload_lds16(A + (size_t)(bm0 + i_ * 32 + srow) * DIM + (kt) * 64 + scol,       \
                  &As[buf][i_ * 32 * 64 + ldst]);                                    \
      gload_lds16(Bt + (size_t)(bn0 + i_ * 32 + srow) * DIM + (kt) * 64 + scol,      \
                  &Bs[buf][i_ * 32 * 64 + ldst]);                                    \
    }                                                                                \
  } while (0)

  STAGE_G(0, 0);
  __syncthreads();

  for (int s = 0; s < 16; ++s) {
    const int cur = s & 1;
    if (s < 15) STAGE_G(cur ^ 1, s + 1);
    bf16x8 a[4][2], b[4][2];
#pragma unroll
    for (int m = 0; m < 4; ++m)
#pragma unroll
      for (int kk = 0; kk < 2; ++kk)
        a[m][kk] = *reinterpret_cast<const bf16x8*>(
            &As[cur][(wm * 64 + m * 16 + lr) * 64 + ((kk * 32 + lg * 8) ^ rsw)]);
#pragma unroll
    for (int n = 0; n < 4; ++n)
#pragma unroll
      for (int kk = 0; kk < 2; ++kk)
        b[n][kk] = *reinterpret_cast<const bf16x8*>(
            &Bs[cur][(wn * 64 + n * 16 + lr) * 64 + ((kk * 32 + lg * 8) ^ rsw)]);
#pragma unroll
    for (int m = 0; m < 4; ++m)
#pragma unroll
      for (int n = 0; n < 4; ++n)
#pragma unroll
        for (int kk = 0; kk < 2; ++kk)
          acc[m][n] = __builtin_amdgcn_mfma_f32_16x16x32_bf16(a[m][kk], b[n][kk],
                                                              acc[m][n], 0, 0, 0);
    __syncthreads();
  }
#undef STAGE_G

#pragma unroll
  for (int n = 0; n < 4; ++n) {
    int col = bn0 + wn * 64 + n * 16 + lr;
    float bv = bias[col];
    float colsum = 0.f;
#pragma unroll
    for (int m = 0; m < 4; ++m)
#pragma unroll
      for (int r = 0; r < 4; ++r) {
        int row = bm0 + wm * 64 + m * 16 + lg * 4 + r;
        bf16_t rb = f2bf(acc[m][n][r] + bv);
        out[(size_t)row * DIM + col] = rb;
        if (which == 2) colsum += bf2f(rb);
      }
    if (which == 2) atomicAdd(&sumv[col], colsum);
  }
}

// ---------------- Wo GEMM: 128x64 tile, BK=64, dbuf, swizzled LDS, f32 direct --------
// grid (16,16) = 256 blocks, 1/CU. No atomics, no memset.
__global__ __launch_bounds__(256) void gemm_wo(const bf16_t* __restrict__ A,
                                               const bf16_t* __restrict__ Bt,
                                               const float* __restrict__ bias,
                                               float* __restrict__ out) {
  __shared__ __align__(16) bf16_t As[2][128 * 64];
  __shared__ __align__(16) bf16_t Bs[2][64 * 64];
  const int t = threadIdx.x;
  const int bm0 = blockIdx.y * 128, bn0 = blockIdx.x * 64;
  const int w = t >> 6, lane = t & 63, lr = lane & 15, lg = lane >> 4;
  const int wm = w >> 1, wn = w & 1;
  const int srow = t >> 3;
  const int scol = swzc((t & 7) * 8, srow);
  const int ldst = srow * 64 + (t & 7) * 8;
  const int rsw = (lr & 7) << 3;

  f32x4 acc[4][2];
#pragma unroll
  for (int m = 0; m < 4; ++m)
#pragma unroll
    for (int n = 0; n < 2; ++n) acc[m][n] = zero4();

#define STAGE_W(buf, kt)                                                             \
  do {                                                                               \
    _Pragma("unroll") for (int i_ = 0; i_ < 4; ++i_)                                 \
      gload_lds16(A + (size_t)(bm0 + i_ * 32 + srow) * DIM + (kt) * 64 + scol,       \
                  &As[buf][i_ * 32 * 64 + ldst]);                                    \
    _Pragma("unroll") for (int i_ = 0; i_ < 2; ++i_)                                 \
      gload_lds16(Bt + (size_t)(bn0 + i_ * 32 + srow) * DIM + (kt) * 64 + scol,      \
                  &Bs[buf][i_ * 32 * 64 + ldst]);                                    \
  } while (0)

  STAGE_W(0, 0);
  __syncthreads();

  for (int s = 0; s < 16; ++s) {
    const int cur = s & 1;
    if (s < 15) STAGE_W(cur ^ 1, s + 1);
    bf16x8 a[4][2], b[2][2];
#pragma unroll
    for (int m = 0; m < 4; ++m)
#pragma unroll
      for (int kk = 0; kk < 2; ++kk)
        a[m][kk] = *reinterpret_cast<const bf16x8*>(
            &As[cur][(wm * 64 + m * 16 + lr) * 64 + ((kk * 32 + lg * 8) ^ rsw)]);
#pragma unroll
    for (int n = 0; n < 2; ++n)
#pragma unroll
      for (int kk = 0; kk < 2; ++kk)
        b[n][kk] = *reinterpret_cast<const bf16x8*>(
            &Bs[cur][(wn * 32 + n * 16 + lr) * 64 + ((kk * 32 + lg * 8) ^ rsw)]);
#pragma unroll
    for (int m = 0; m < 4; ++m)
#pragma unroll
      for (int n = 0; n < 2; ++n)
#pragma unroll
        for (int kk = 0; kk < 2; ++kk)
          acc[m][n] = __builtin_amdgcn_mfma_f32_16x16x32_bf16(a[m][kk], b[n][kk],
                                                              acc[m][n], 0, 0, 0);
    __syncthreads();
  }
#undef STAGE_W

#pragma unroll
  for (int n = 0; n < 2; ++n) {
    int col = bn0 + wn * 32 + n * 16 + lr;
    float bv = bias[col];
#pragma unroll
    for (int m = 0; m < 4; ++m)
#pragma unroll
      for (int r = 0; r < 4; ++r) {
        int row = bm0 + wm * 64 + m * 16 + lg * 4 + r;
        out[(size_t)row * DIM + col] = acc[m][n][r] + bv;
      }
  }
}

// ---------------- attn v6: swapped-operand MFMA, 32-row blocks, natural VGPR ---------
// 256 threads = 4 waves; 32 q-rows x one head; wave w owns k-chunks [w*8, w*8+8).
// mfma(K,Q): lane holds q-row = m*16 + (lane&15), k = kc*64 + n*16 + (lane>>4)*4 + r.
#define LOADK(buf, kc)                                                              \
  do {                                                                              \
    _Pragma("unroll") for (int n_ = 0; n_ < 4; ++n_)                                \
      _Pragma("unroll") for (int k_ = 0; k_ < 2; ++k_)                              \
        kf[buf][n_][k_] = *reinterpret_cast<const bf16x8*>(                         \
            kp + (size_t)((kc) * 64 + n_ * 16 + lr) * DIM + k_ * 32 + lg * 8);      \
  } while (0)

__global__ __launch_bounds__(256, 2) void attn_kernel(const bf16_t* __restrict__ q,
                                                      const bf16_t* __restrict__ k,
                                                      const bf16_t* __restrict__ v,
                                                      const float* __restrict__ sumv,
                                                      bf16_t* __restrict__ op) {
  __shared__ float CM[QR * 33];
  __shared__ float Tsh[QR];
  __shared__ float zsh[QR];
  __shared__ int   cnt[QR];
  __shared__ float cval[QR * CST];
  __shared__ unsigned short cidx[QR * CST];

  const int t = threadIdx.x;
  // XCD-aware bijective remap (1024 blocks): 2 heads per XCD -> head slices L2-resident
  const int lin = blockIdx.x;
  const int xcd = lin & 7, ixd = lin >> 3;
  const int h = xcd * 2 + (ixd >> 6), qt = ixd & 63;
  const int w = t >> 6, lane = t & 63, lr = lane & 15, lg = lane >> 4;

  const bf16_t* qp = q + (size_t)(qt * QR) * DIM + h * HDIM;
  const bf16_t* kp = k + h * HDIM;

  bf16x8 aq[2][2];
#pragma unroll
  for (int m = 0; m < 2; ++m)
#pragma unroll
    for (int kk = 0; kk < 2; ++kk)
      aq[m][kk] = *reinterpret_cast<const bf16x8*>(
          qp + (size_t)(m * 16 + lr) * DIM + kk * 32 + lg * 8);

  bf16x8 kf[2][4][2];

  // ---- pass 1: per-(row,chunk) maxima (swapped mfma -> in-lane max + 2 shfl) ----
  LOADK(0, w * 8);
#pragma unroll
  for (int i = 0; i < 8; ++i) {
    if (i < 7) LOADK((i + 1) & 1, w * 8 + i + 1);
    const int cur = i & 1;
    f32x4 sacc[2][4];
#pragma unroll
    for (int m = 0; m < 2; ++m)
#pragma unroll
      for (int n = 0; n < 4; ++n) sacc[m][n] = zero4();
#pragma unroll
    for (int m = 0; m < 2; ++m)
#pragma unroll
      for (int n = 0; n < 4; ++n)
#pragma unroll
        for (int kk = 0; kk < 2; ++kk)
          sacc[m][n] = __builtin_amdgcn_mfma_f32_16x16x32_bf16(kf[cur][n][kk], aq[m][kk],
                                                               sacc[m][n], 0, 0, 0);
#pragma unroll
    for (int m = 0; m < 2; ++m) {
      float mx = sacc[m][0][0];
#pragma unroll
      for (int n = 0; n < 4; ++n)
#pragma unroll
        for (int r = 0; r < 4; ++r) mx = fmaxf(mx, sacc[m][n][r]);
      mx = fmaxf(mx, __shfl_xor(mx, 16));
      mx = fmaxf(mx, __shfl_xor(mx, 32));
      if (lane < 16) CM[(m * 16 + lane) * 33 + (w * 8 + i)] = mx * 0.125f;
    }
  }
  LOADK(0, w * 8);  // prefetch pass-2 first tile across the threshold phase
  __syncthreads();

  // ---- threshold: T = 16th-largest chunk-max, 8 lanes per row ----
  {
    const int trow = t >> 3, tsub = t & 7;
    float cmv[4];
#pragma unroll
    for (int c = 0; c < 4; ++c) cmv[c] = CM[trow * 33 + tsub * 4 + c];
    float Tval = -1e30f;
#pragma unroll
    for (int it = 0; it < TOPK; ++it) {
      float lm = fmaxf(fmaxf(cmv[0], cmv[1]), fmaxf(cmv[2], cmv[3]));
      float gm = fmaxf(lm, __shfl_xor(lm, 1));
      gm = fmaxf(gm, __shfl_xor(gm, 2));
      gm = fmaxf(gm, __shfl_xor(gm, 4));
      u64 b = __ballot(lm == gm);
      int base = lane & ~7;
      int ownsub = __ffsll((b >> base) & 0xFFull) - 1;
      if (tsub == ownsub) {
        bool d = false;
#pragma unroll
        for (int c = 0; c < 4; ++c)
          if (!d && cmv[c] == lm) { cmv[c] = -1e30f; d = true; }
      }
      Tval = gm;
    }
    if (tsub == 0) { Tsh[trow] = Tval; cnt[trow] = 0; }
  }
  __syncthreads();

  float Treg[2];
#pragma unroll
  for (int m = 0; m < 2; ++m) Treg[m] = Tsh[m * 16 + lr];

  // ---- pass 2: recompute scores, collect candidates >= T ----
#pragma unroll
  for (int i = 0; i < 8; ++i) {
    if (i < 7) LOADK((i + 1) & 1, w * 8 + i + 1);
    const int cur = i & 1;
    const int kc = w * 8 + i;
    f32x4 sacc[2][4];
#pragma unroll
    for (int m = 0; m < 2; ++m)
#pragma unroll
      for (int n = 0; n < 4; ++n) sacc[m][n] = zero4();
#pragma unroll
    for (int m = 0; m < 2; ++m)
#pragma unroll
      for (int n = 0; n < 4; ++n)
#pragma unroll
        for (int kk = 0; kk < 2; ++kk)
          sacc[m][n] = __builtin_amdgcn_mfma_f32_16x16x32_bf16(kf[cur][n][kk], aq[m][kk],
                                                               sacc[m][n], 0, 0, 0);
#pragma unroll
    for (int m = 0; m < 2; ++m)
#pragma unroll
      for (int n = 0; n < 4; ++n)
#pragma unroll
        for (int r = 0; r < 4; ++r) {
          float val = sacc[m][n][r] * 0.125f;
          if (val >= Treg[m]) {
            int row = m * 16 + lr;
            int p = atomicAdd(&cnt[row], 1);
            if (p < CAP) {
              cval[row * CST + p] = val;
              cidx[row * CST + p] = (unsigned short)(kc * 64 + n * 16 + lg * 4 + r);
            }
          }
        }
  }
  __syncthreads();

  // ---- pass 3: exact top-16 (value order, lower-index tie-break), 8 lanes/row ----
  {
    const int trow = t >> 3, tsub = t & 7;
    int nc = cnt[trow]; if (nc > CAP) nc = CAP;
    float Zexp = 0.f;
    for (int sel = 0; sel < TOPK; ++sel) {
      u64 lmax = 0ull; int lp = -1;
      for (int p = tsub; p < nc; p += 8) {
        float vv = cval[trow * CST + p];
        unsigned id = cidx[trow * CST + p];
        u64 key = ((u64)ordf(vv) << 32) | (u64)(unsigned)(~id);
        if (key > lmax) { lmax = key; lp = p; }
      }
      u64 g = lmax;
#pragma unroll
      for (int d = 1; d < 8; d <<= 1) {
        u64 o = __shfl_xor(g, d);
        g = (o > g) ? o : g;
      }
      if (lmax == g && lp >= 0) cval[trow * CST + lp] = -1e30f;
      float val = iordf((unsigned)(g >> 32));
      int idx = (int)(~(unsigned)(g & 0xffffffffull));
      float e = expf(val);
      Zexp += e;
      if (tsub == 0) {
        CM[trow * 33 + sel] = e - 1.f;
        CM[trow * 33 + 16 + sel] = __int_as_float(idx);
      }
    }
    if (tsub == 0) zsh[trow] = 2032.f + Zexp;  // (2048-16) zeros give exp(0)=1
  }
  __syncthreads();

  // ---- pass 4: out = (sumv + sum_j w_j * v[idx_j]) / Z ----
  {
    const int row = t >> 3;
    const int dbase = h * HDIM + (t & 7) * 8;
    float oacc[8];
    const float4* sp = reinterpret_cast<const float4*>(sumv + dbase);
    float4 s0 = sp[0], s1 = sp[1];
    oacc[0] = s0.x; oacc[1] = s0.y; oacc[2] = s0.z; oacc[3] = s0.w;
    oacc[4] = s1.x; oacc[5] = s1.y; oacc[6] = s1.z; oacc[7] = s1.w;
    float invZ = 1.f / zsh[row];
#pragma unroll
    for (int j = 0; j < TOPK; ++j) {
      float wj = CM[row * 33 + j];
      int kidx = __float_as_int(CM[row * 33 + 16 + j]);
      bf16x8 vv = *reinterpret_cast<const bf16x8*>(v + (size_t)kidx * DIM + dbase);
#pragma unroll
      for (int e = 0; e < 8; ++e) oacc[e] += wj * bf2f((bf16_t)vv[e]);
    }
    bf16x8 o0;
#pragma unroll
    for (int e = 0; e < 8; ++e) o0[e] = (short)f2bf(oacc[e] * invZ);
    *reinterpret_cast<bf16x8*>(op + (size_t)(qt * QR + row) * DIM + dbase) = o0;
  }
}

extern "C" void kernel_launch(void* const* d_in, const int* in_sizes, int n_in,
                              void* d_out, int out_size, void* d_ws, size_t ws_size,
                              hipStream_t stream) {
  const float* x  = (const float*)d_in[0];
  const float* Wq = (const float*)d_in[1];
  const float* bq = (const float*)d_in[2];
  const float* Wk = (const float*)d_in[3];
  const float* bk = (const float*)d_in[4];
  const float* Wv = (const float*)d_in[5];
  const float* bv = (const float*)d_in[6];
  const float* Wo = (const float*)d_in[7];
  const float* bo = (const float*)d_in[8];
  float* out = (float*)d_out;

  char* ws = (char*)d_ws;
  bf16_t* xb   = (bf16_t*)(ws + (size_t)(0)  * (1 << 20));
  bf16_t* WqT  = (bf16_t*)(ws + (size_t)(4)  * (1 << 20));
  bf16_t* WkT  = (bf16_t*)(ws + (size_t)(6)  * (1 << 20));
  bf16_t* WvT  = (bf16_t*)(ws + (size_t)(8)  * (1 << 20));
  bf16_t* WoT  = (bf16_t*)(ws + (size_t)(10) * (1 << 20));
  bf16_t* qb   = (bf16_t*)(ws + (size_t)(12) * (1 << 20));
  bf16_t* kb   = (bf16_t*)(ws + (size_t)(16) * (1 << 20));
  bf16_t* vb   = (bf16_t*)(ws + (size_t)(20) * (1 << 20));
  bf16_t* opb  = (bf16_t*)(ws + (size_t)(24) * (1 << 20));
  float*  sumv = (float*) (ws + (size_t)(28) * (1 << 20));

  prep_kernel<<<dim3(32, 32, 5), dim3(32, 8), 0, stream>>>(x, xb, Wq, Wk, Wv, Wo,
                                                           WqT, WkT, WvT, WoT);
  hipMemsetAsync(sumv, 0, DIM * sizeof(float), stream);

  gemm_qkv<<<dim3(24, 16), 256, 0, stream>>>(xb, WqT, WkT, WvT, bq, bk, bv,
                                             qb, kb, vb, sumv);

  attn_kernel<<<1024, 256, 0, stream>>>(qb, kb, vb, sumv, opb);

  gemm_wo<<<dim3(16, 16), 256, 0, stream>>>(opb, WoT, bo, out);
}

// Round 8
// 213.074 us; speedup vs baseline: 1.1980x; 1.0905x over previous
//
#include <hip/hip_runtime.h>
#include <stdint.h>

constexpr int SEQ  = 2048;
constexpr int DIM  = 1024;
constexpr int NH   = 16;
constexpr int HDIM = 64;
constexpr int TOPK = 16;
constexpr int CAP  = 96;   // candidate buffer per row (expected fill ~20-40)
constexpr int CST  = 97;   // padded stride
constexpr int QR   = 64;   // q-rows per attn block (R5 shape: latency-hiding sweet spot)

typedef unsigned short bf16_t;
typedef __attribute__((ext_vector_type(8))) short bf16x8;
typedef __attribute__((ext_vector_type(4))) float f32x4;
typedef unsigned long long u64;

// T2 XOR swizzle (round-2: GEMM LDS conflicts 1.28e7 -> 1.9e5)
__device__ __forceinline__ int swzc(int col, int row) { return col ^ ((row & 7) << 3); }

__device__ __forceinline__ float bf2f(bf16_t b) {
  return __uint_as_float(((unsigned)b) << 16);
}
__device__ __forceinline__ bf16_t f2bf(float f) {
  unsigned u = __float_as_uint(f);
  unsigned r = u + 0x7fffu + ((u >> 16) & 1u);
  return (bf16_t)(r >> 16);
}
__device__ __forceinline__ f32x4 zero4() {
  f32x4 z; z[0] = 0.f; z[1] = 0.f; z[2] = 0.f; z[3] = 0.f; return z;
}
__device__ __forceinline__ void gload_lds16(const bf16_t* g, bf16_t* l) {
  __builtin_amdgcn_global_load_lds(
      (const __attribute__((address_space(1))) void*)g,
      (__attribute__((address_space(3))) void*)l, 16, 0, 0);
}
// monotone float->uint order transform
__device__ __forceinline__ unsigned ordf(float f) {
  unsigned b = __float_as_uint(f);
  return (b & 0x80000000u) ? ~b : (b | 0x80000000u);
}
__device__ __forceinline__ float iordf(unsigned u) {
  unsigned b = (u & 0x80000000u) ? (u ^ 0x80000000u) : ~u;
  return __uint_as_float(b);
}

// ---------------- prep: weight transpose+cast (z<4) and x cast (z==4) ----------------
__global__ void prep_kernel(const float* __restrict__ x, bf16_t* __restrict__ xb,
                            const float* __restrict__ W0, const float* __restrict__ W1,
                            const float* __restrict__ W2, const float* __restrict__ W3,
                            bf16_t* __restrict__ T0, bf16_t* __restrict__ T1,
                            bf16_t* __restrict__ T2, bf16_t* __restrict__ T3) {
  const int z = blockIdx.z;
  if (z == 4) {
    int bl = blockIdx.y * 32 + blockIdx.x;
    int tt = threadIdx.y * 32 + threadIdx.x;
    int i = (bl * 256 + tt) * 8;
    float4 v0 = *reinterpret_cast<const float4*>(x + i);
    float4 v1 = *reinterpret_cast<const float4*>(x + i + 4);
    bf16x8 o;
    o[0] = (short)f2bf(v0.x); o[1] = (short)f2bf(v0.y);
    o[2] = (short)f2bf(v0.z); o[3] = (short)f2bf(v0.w);
    o[4] = (short)f2bf(v1.x); o[5] = (short)f2bf(v1.y);
    o[6] = (short)f2bf(v1.z); o[7] = (short)f2bf(v1.w);
    *reinterpret_cast<bf16x8*>(xb + i) = o;
    return;
  }
  const float* W = (z == 0) ? W0 : (z == 1) ? W1 : (z == 2) ? W2 : W3;
  bf16_t* WT = (z == 0) ? T0 : (z == 1) ? T1 : (z == 2) ? T2 : T3;
  __shared__ float tile[32][33];
  int tx = threadIdx.x, ty = threadIdx.y;
  int bx = blockIdx.x * 32, by = blockIdx.y * 32;
#pragma unroll
  for (int i = 0; i < 4; ++i)
    tile[ty + i * 8][tx] = W[(by + ty + i * 8) * DIM + bx + tx];
  __syncthreads();
#pragma unroll
  for (int i = 0; i < 4; ++i)
    WT[(bx + ty + i * 8) * DIM + by + tx] = f2bf(tile[tx][ty + i * 8]);
}

// ---------------- QKV GEMM: 128x128 tile, BK=64, dbuf, swizzled LDS ------------------
// grid (24,16): which = x>>3 selects {Wq,Wk,Wv}; V col-sums fused via atomics.
__global__ __launch_bounds__(256) void gemm_qkv(const bf16_t* __restrict__ A,
                                                const bf16_t* __restrict__ B0,
                                                const bf16_t* __restrict__ B1,
                                                const bf16_t* __restrict__ B2,
                                                const float* __restrict__ c0,
                                                const float* __restrict__ c1,
                                                const float* __restrict__ c2,
                                                bf16_t* __restrict__ o0,
                                                bf16_t* __restrict__ o1,
                                                bf16_t* __restrict__ o2,
                                                float* __restrict__ sumv) {
  __shared__ __align__(16) bf16_t As[2][128 * 64];
  __shared__ __align__(16) bf16_t Bs[2][128 * 64];
  const int t = threadIdx.x;
  const int which = blockIdx.x >> 3;
  const bf16_t* Bt = (which == 0) ? B0 : (which == 1) ? B1 : B2;
  const float* bias = (which == 0) ? c0 : (which == 1) ? c1 : c2;
  bf16_t* out = (which == 0) ? o0 : (which == 1) ? o1 : o2;
  const int bm0 = blockIdx.y * 128, bn0 = (blockIdx.x & 7) * 128;
  const int w = t >> 6, lane = t & 63, lr = lane & 15, lg = lane >> 4;
  const int wm = w >> 1, wn = w & 1;
  const int srow = t >> 3;
  const int scol = swzc((t & 7) * 8, srow);
  const int ldst = srow * 64 + (t & 7) * 8;
  const int rsw = (lr & 7) << 3;

  f32x4 acc[4][4];
#pragma unroll
  for (int m = 0; m < 4; ++m)
#pragma unroll
    for (int n = 0; n < 4; ++n) acc[m][n] = zero4();

#define STAGE_G(buf, kt)                                                             \
  do {                                                                               \
    _Pragma("unroll") for (int i_ = 0; i_ < 4; ++i_) {                               \
      gload_lds16(A + (size_t)(bm0 + i_ * 32 + srow) * DIM + (kt) * 64 + scol,       \
                  &As[buf][i_ * 32 * 64 + ldst]);                                    \
      gload_lds16(Bt + (size_t)(bn0 + i_ * 32 + srow) * DIM + (kt) * 64 + scol,      \
                  &Bs[buf][i_ * 32 * 64 + ldst]);                                    \
    }                                                                                \
  } while (0)

  STAGE_G(0, 0);
  __syncthreads();

  for (int s = 0; s < 16; ++s) {
    const int cur = s & 1;
    if (s < 15) STAGE_G(cur ^ 1, s + 1);
    bf16x8 a[4][2], b[4][2];
#pragma unroll
    for (int m = 0; m < 4; ++m)
#pragma unroll
      for (int kk = 0; kk < 2; ++kk)
        a[m][kk] = *reinterpret_cast<const bf16x8*>(
            &As[cur][(wm * 64 + m * 16 + lr) * 64 + ((kk * 32 + lg * 8) ^ rsw)]);
#pragma unroll
    for (int n = 0; n < 4; ++n)
#pragma unroll
      for (int kk = 0; kk < 2; ++kk)
        b[n][kk] = *reinterpret_cast<const bf16x8*>(
            &Bs[cur][(wn * 64 + n * 16 + lr) * 64 + ((kk * 32 + lg * 8) ^ rsw)]);
#pragma unroll
    for (int m = 0; m < 4; ++m)
#pragma unroll
      for (int n = 0; n < 4; ++n)
#pragma unroll
        for (int kk = 0; kk < 2; ++kk)
          acc[m][n] = __builtin_amdgcn_mfma_f32_16x16x32_bf16(a[m][kk], b[n][kk],
                                                              acc[m][n], 0, 0, 0);
    __syncthreads();
  }
#undef STAGE_G

#pragma unroll
  for (int n = 0; n < 4; ++n) {
    int col = bn0 + wn * 64 + n * 16 + lr;
    float bv = bias[col];
    float colsum = 0.f;
#pragma unroll
    for (int m = 0; m < 4; ++m)
#pragma unroll
      for (int r = 0; r < 4; ++r) {
        int row = bm0 + wm * 64 + m * 16 + lg * 4 + r;
        bf16_t rb = f2bf(acc[m][n][r] + bv);
        out[(size_t)row * DIM + col] = rb;
        if (which == 2) colsum += bf2f(rb);
      }
    if (which == 2) atomicAdd(&sumv[col], colsum);
  }
}

// ---------------- Wo GEMM: 128x64 tile, BK=64, dbuf, swizzled LDS, f32 direct --------
// grid (16,16) = 256 blocks, 1/CU. No atomics, no memset.
__global__ __launch_bounds__(256) void gemm_wo(const bf16_t* __restrict__ A,
                                               const bf16_t* __restrict__ Bt,
                                               const float* __restrict__ bias,
                                               float* __restrict__ out) {
  __shared__ __align__(16) bf16_t As[2][128 * 64];
  __shared__ __align__(16) bf16_t Bs[2][64 * 64];
  const int t = threadIdx.x;
  const int bm0 = blockIdx.y * 128, bn0 = blockIdx.x * 64;
  const int w = t >> 6, lane = t & 63, lr = lane & 15, lg = lane >> 4;
  const int wm = w >> 1, wn = w & 1;
  const int srow = t >> 3;
  const int scol = swzc((t & 7) * 8, srow);
  const int ldst = srow * 64 + (t & 7) * 8;
  const int rsw = (lr & 7) << 3;

  f32x4 acc[4][2];
#pragma unroll
  for (int m = 0; m < 4; ++m)
#pragma unroll
    for (int n = 0; n < 2; ++n) acc[m][n] = zero4();

#define STAGE_W(buf, kt)                                                             \
  do {                                                                               \
    _Pragma("unroll") for (int i_ = 0; i_ < 4; ++i_)                                 \
      gload_lds16(A + (size_t)(bm0 + i_ * 32 + srow) * DIM + (kt) * 64 + scol,       \
                  &As[buf][i_ * 32 * 64 + ldst]);                                    \
    _Pragma("unroll") for (int i_ = 0; i_ < 2; ++i_)                                 \
      gload_lds16(Bt + (size_t)(bn0 + i_ * 32 + srow) * DIM + (kt) * 64 + scol,      \
                  &Bs[buf][i_ * 32 * 64 + ldst]);                                    \
  } while (0)

  STAGE_W(0, 0);
  __syncthreads();

  for (int s = 0; s < 16; ++s) {
    const int cur = s & 1;
    if (s < 15) STAGE_W(cur ^ 1, s + 1);
    bf16x8 a[4][2], b[2][2];
#pragma unroll
    for (int m = 0; m < 4; ++m)
#pragma unroll
      for (int kk = 0; kk < 2; ++kk)
        a[m][kk] = *reinterpret_cast<const bf16x8*>(
            &As[cur][(wm * 64 + m * 16 + lr) * 64 + ((kk * 32 + lg * 8) ^ rsw)]);
#pragma unroll
    for (int n = 0; n < 2; ++n)
#pragma unroll
      for (int kk = 0; kk < 2; ++kk)
        b[n][kk] = *reinterpret_cast<const bf16x8*>(
            &Bs[cur][(wn * 32 + n * 16 + lr) * 64 + ((kk * 32 + lg * 8) ^ rsw)]);
#pragma unroll
    for (int m = 0; m < 4; ++m)
#pragma unroll
      for (int n = 0; n < 2; ++n)
#pragma unroll
        for (int kk = 0; kk < 2; ++kk)
          acc[m][n] = __builtin_amdgcn_mfma_f32_16x16x32_bf16(a[m][kk], b[n][kk],
                                                              acc[m][n], 0, 0, 0);
    __syncthreads();
  }
#undef STAGE_W

#pragma unroll
  for (int n = 0; n < 2; ++n) {
    int col = bn0 + wn * 32 + n * 16 + lr;
    float bv = bias[col];
#pragma unroll
    for (int m = 0; m < 4; ++m)
#pragma unroll
      for (int r = 0; r < 4; ++r) {
        int row = bm0 + wm * 64 + m * 16 + lg * 4 + r;
        out[(size_t)row * DIM + col] = acc[m][n][r] + bv;
      }
  }
}

// ---------------- attn v7: QR=64 (R5 shape) + swapped-operand MFMA (R7 math) ---------
// 256 threads = 4 waves; 64 q-rows x one head; wave w owns k-chunks [w*8, w*8+8).
// mfma(K,Q): q-row = m*16 + (lane&15), k = kc*64 + n*16 + (lane>>4)*4 + r.
#define LOADK(buf, kc)                                                              \
  do {                                                                              \
    _Pragma("unroll") for (int n_ = 0; n_ < 4; ++n_)                                \
      _Pragma("unroll") for (int k_ = 0; k_ < 2; ++k_)                              \
        kf[buf][n_][k_] = *reinterpret_cast<const bf16x8*>(                         \
            kp + (size_t)((kc) * 64 + n_ * 16 + lr) * DIM + k_ * 32 + lg * 8);      \
  } while (0)

__global__ __launch_bounds__(256, 2) void attn_kernel(const bf16_t* __restrict__ q,
                                                      const bf16_t* __restrict__ k,
                                                      const bf16_t* __restrict__ v,
                                                      const float* __restrict__ sumv,
                                                      bf16_t* __restrict__ op) {
  __shared__ float CM[QR * 33];
  __shared__ float Tsh[QR];
  __shared__ float zsh[QR];
  __shared__ int   cnt[QR];
  __shared__ float cval[QR * CST];
  __shared__ unsigned short cidx[QR * CST];

  const int t = threadIdx.x;
  // XCD-aware bijective remap (512 blocks): 2 heads per XCD -> head slices L2-resident
  const int lin = blockIdx.x;
  const int xcd = lin & 7, ixd = lin >> 3;
  const int h = xcd * 2 + (ixd >> 5), qt = ixd & 31;
  const int w = t >> 6, lane = t & 63, lr = lane & 15, lg = lane >> 4;

  const bf16_t* qp = q + (size_t)(qt * QR) * DIM + h * HDIM;
  const bf16_t* kp = k + h * HDIM;

  // Q fragments (B-operand in swapped mfma): all 64 rows
  bf16x8 aq[4][2];
#pragma unroll
  for (int m = 0; m < 4; ++m)
#pragma unroll
    for (int kk = 0; kk < 2; ++kk)
      aq[m][kk] = *reinterpret_cast<const bf16x8*>(
          qp + (size_t)(m * 16 + lr) * DIM + kk * 32 + lg * 8);

  bf16x8 kf[2][4][2];

  // ---- pass 1: per-(row,chunk) maxima (swapped mfma -> in-lane max + 2 shfl) ----
  LOADK(0, w * 8);
#pragma unroll
  for (int i = 0; i < 8; ++i) {
    if (i < 7) LOADK((i + 1) & 1, w * 8 + i + 1);
    const int cur = i & 1;
    f32x4 sacc[4][4];
#pragma unroll
    for (int m = 0; m < 4; ++m)
#pragma unroll
      for (int n = 0; n < 4; ++n) sacc[m][n] = zero4();
#pragma unroll
    for (int m = 0; m < 4; ++m)
#pragma unroll
      for (int n = 0; n < 4; ++n)
#pragma unroll
        for (int kk = 0; kk < 2; ++kk)
          sacc[m][n] = __builtin_amdgcn_mfma_f32_16x16x32_bf16(kf[cur][n][kk], aq[m][kk],
                                                               sacc[m][n], 0, 0, 0);
#pragma unroll
    for (int m = 0; m < 4; ++m) {
      float mx = sacc[m][0][0];
#pragma unroll
      for (int n = 0; n < 4; ++n)
#pragma unroll
        for (int r = 0; r < 4; ++r) mx = fmaxf(mx, sacc[m][n][r]);
      mx = fmaxf(mx, __shfl_xor(mx, 16));
      mx = fmaxf(mx, __shfl_xor(mx, 32));
      if (lane < 16) CM[(m * 16 + lane) * 33 + (w * 8 + i)] = mx * 0.125f;
    }
  }
  LOADK(0, w * 8);  // prefetch pass-2 first tile across the threshold phase
  __syncthreads();

  // ---- threshold: T = 16th-largest chunk-max, 4 lanes per row ----
  {
    const int trow = t >> 2, tsub = t & 3;
    float cmv[8];
#pragma unroll
    for (int c = 0; c < 8; ++c) cmv[c] = CM[trow * 33 + tsub * 8 + c];
    float Tval = -1e30f;
#pragma unroll
    for (int it = 0; it < TOPK; ++it) {
      float lm = cmv[0];
#pragma unroll
      for (int c = 1; c < 8; ++c) lm = fmaxf(lm, cmv[c]);
      float gm = fmaxf(lm, __shfl_xor(lm, 1));
      gm = fmaxf(gm, __shfl_xor(gm, 2));
      u64 b = __ballot(lm == gm);
      int base = lane & ~3;
      int ownsub = __ffsll((b >> base) & 0xFull) - 1;
      if (tsub == ownsub) {
        bool d = false;
#pragma unroll
        for (int c = 0; c < 8; ++c)
          if (!d && cmv[c] == lm) { cmv[c] = -1e30f; d = true; }
      }
      Tval = gm;
    }
    if (tsub == 0) { Tsh[trow] = Tval; cnt[trow] = 0; }
  }
  __syncthreads();

  float Treg[4];
#pragma unroll
  for (int m = 0; m < 4; ++m) Treg[m] = Tsh[m * 16 + lr];

  // ---- pass 2: recompute scores, collect candidates >= T ----
#pragma unroll
  for (int i = 0; i < 8; ++i) {
    if (i < 7) LOADK((i + 1) & 1, w * 8 + i + 1);
    const int cur = i & 1;
    const int kc = w * 8 + i;
    f32x4 sacc[4][4];
#pragma unroll
    for (int m = 0; m < 4; ++m)
#pragma unroll
      for (int n = 0; n < 4; ++n) sacc[m][n] = zero4();
#pragma unroll
    for (int m = 0; m < 4; ++m)
#pragma unroll
      for (int n = 0; n < 4; ++n)
#pragma unroll
        for (int kk = 0; kk < 2; ++kk)
          sacc[m][n] = __builtin_amdgcn_mfma_f32_16x16x32_bf16(kf[cur][n][kk], aq[m][kk],
                                                               sacc[m][n], 0, 0, 0);
#pragma unroll
    for (int m = 0; m < 4; ++m)
#pragma unroll
      for (int n = 0; n < 4; ++n)
#pragma unroll
        for (int r = 0; r < 4; ++r) {
          float val = sacc[m][n][r] * 0.125f;
          if (val >= Treg[m]) {
            int row = m * 16 + lr;
            int p = atomicAdd(&cnt[row], 1);
            if (p < CAP) {
              cval[row * CST + p] = val;
              cidx[row * CST + p] = (unsigned short)(kc * 64 + n * 16 + lg * 4 + r);
            }
          }
        }
  }
  __syncthreads();

  // ---- pass 3: exact top-16 (value order, lower-index tie-break), 4 lanes/row ----
  {
    const int trow = t >> 2, tsub = t & 3;
    int nc = cnt[trow]; if (nc > CAP) nc = CAP;
    float Zexp = 0.f;
    for (int sel = 0; sel < TOPK; ++sel) {
      u64 lmax = 0ull; int lp = -1;
      for (int p = tsub; p < nc; p += 4) {
        float vv = cval[trow * CST + p];
        unsigned id = cidx[trow * CST + p];
        u64 key = ((u64)ordf(vv) << 32) | (u64)(unsigned)(~id);
        if (key > lmax) { lmax = key; lp = p; }
      }
      u64 g = lmax;
#pragma unroll
      for (int d = 1; d < 4; d <<= 1) {
        u64 o = __shfl_xor(g, d);
        g = (o > g) ? o : g;
      }
      if (lmax == g && lp >= 0) cval[trow * CST + lp] = -1e30f;
      float val = iordf((unsigned)(g >> 32));
      int idx = (int)(~(unsigned)(g & 0xffffffffull));
      float e = expf(val);
      Zexp += e;
      if (tsub == 0) {
        CM[trow * 33 + sel] = e - 1.f;
        CM[trow * 33 + 16 + sel] = __int_as_float(idx);
      }
    }
    if (tsub == 0) zsh[trow] = 2032.f + Zexp;  // (2048-16) zeros give exp(0)=1
  }
  __syncthreads();

  // ---- pass 4: out = (sumv + sum_j w_j * v[idx_j]) / Z ----
  {
    const int row = t >> 2;
    const int dbase = h * HDIM + (t & 3) * 16;
    float oacc[16];
    const float4* sp = reinterpret_cast<const float4*>(sumv + dbase);
#pragma unroll
    for (int u = 0; u < 4; ++u) {
      float4 s4 = sp[u];
      oacc[u * 4 + 0] = s4.x; oacc[u * 4 + 1] = s4.y;
      oacc[u * 4 + 2] = s4.z; oacc[u * 4 + 3] = s4.w;
    }
    float invZ = 1.f / zsh[row];
#pragma unroll
    for (int j = 0; j < TOPK; ++j) {
      float wj = CM[row * 33 + j];
      int kidx = __float_as_int(CM[row * 33 + 16 + j]);
      const bf16x8* vp = reinterpret_cast<const bf16x8*>(v + (size_t)kidx * DIM + dbase);
      bf16x8 v0 = vp[0], v1 = vp[1];
#pragma unroll
      for (int e = 0; e < 8; ++e) {
        oacc[e] += wj * bf2f((bf16_t)v0[e]);
        oacc[8 + e] += wj * bf2f((bf16_t)v1[e]);
      }
    }
    bf16x8 o0, o1;
#pragma unroll
    for (int e = 0; e < 8; ++e) {
      o0[e] = (short)f2bf(oacc[e] * invZ);
      o1[e] = (short)f2bf(oacc[8 + e] * invZ);
    }
    bf16_t* orow = op + (size_t)(qt * QR + row) * DIM + dbase;
    *reinterpret_cast<bf16x8*>(orow) = o0;
    *reinterpret_cast<bf16x8*>(orow + 8) = o1;
  }
}

extern "C" void kernel_launch(void* const* d_in, const int* in_sizes, int n_in,
                              void* d_out, int out_size, void* d_ws, size_t ws_size,
                              hipStream_t stream) {
  const float* x  = (const float*)d_in[0];
  const float* Wq = (const float*)d_in[1];
  const float* bq = (const float*)d_in[2];
  const float* Wk = (const float*)d_in[3];
  const float* bk = (const float*)d_in[4];
  const float* Wv = (const float*)d_in[5];
  const float* bv = (const float*)d_in[6];
  const float* Wo = (const float*)d_in[7];
  const float* bo = (const float*)d_in[8];
  float* out = (float*)d_out;

  char* ws = (char*)d_ws;
  bf16_t* xb   = (bf16_t*)(ws + (size_t)(0)  * (1 << 20));
  bf16_t* WqT  = (bf16_t*)(ws + (size_t)(4)  * (1 << 20));
  bf16_t* WkT  = (bf16_t*)(ws + (size_t)(6)  * (1 << 20));
  bf16_t* WvT  = (bf16_t*)(ws + (size_t)(8)  * (1 << 20));
  bf16_t* WoT  = (bf16_t*)(ws + (size_t)(10) * (1 << 20));
  bf16_t* qb   = (bf16_t*)(ws + (size_t)(12) * (1 << 20));
  bf16_t* kb   = (bf16_t*)(ws + (size_t)(16) * (1 << 20));
  bf16_t* vb   = (bf16_t*)(ws + (size_t)(20) * (1 << 20));
  bf16_t* opb  = (bf16_t*)(ws + (size_t)(24) * (1 << 20));
  float*  sumv = (float*) (ws + (size_t)(28) * (1 << 20));

  prep_kernel<<<dim3(32, 32, 5), dim3(32, 8), 0, stream>>>(x, xb, Wq, Wk, Wv, Wo,
                                                           WqT, WkT, WvT, WoT);
  hipMemsetAsync(sumv, 0, DIM * sizeof(float), stream);

  gemm_qkv<<<dim3(24, 16), 256, 0, stream>>>(xb, WqT, WkT, WvT, bq, bk, bv,
                                             qb, kb, vb, sumv);

  attn_kernel<<<512, 256, 0, stream>>>(qb, kb, vb, sumv, opb);

  gemm_wo<<<dim3(16, 16), 256, 0, stream>>>(opb, WoT, bo, out);
}